// Round 1
// baseline (243.603 us; speedup 1.0000x reference)
//
#include <hip/hip_runtime.h>
#include <math.h>

// 1D grayscale dilation (max-plus conv), K=11, halo=5, fp32.
// out[i] = max_j ( x[i-5+j] + h[j] ),  h[j] = -(j-5)^2 / (4*scale)
// Memory-bound streaming kernel: 16 outputs/thread via 4x float4 stores,
// inputs via 8 aligned float4 loads covering [base-8, base+24).

#define KSZ 11
#define HALF 5
#define VEC 16          // outputs per thread
#define NLOAD 8         // aligned float4 loads per thread (covers VEC + 2*HALF with slack)

__global__ __launch_bounds__(256) void dilate1d_kernel(
    const float4* __restrict__ x4,
    const float*  __restrict__ scale_p,
    float4*       __restrict__ out4,
    int n4)   // number of float4 elements in x / out
{
    const float s = scale_p[0];
    float h[KSZ];
#pragma unroll
    for (int j = 0; j < KSZ; ++j) {
        float z = (float)(j - HALF);
        h[j] = -(z * z) / (4.0f * s);
    }

    // first output float4 index this thread owns
    int q0 = (blockIdx.x * blockDim.x + threadIdx.x) * (VEC / 4);
    if (q0 >= n4) return;

    const float NEG = -INFINITY;

    // Stage 32 input floats: x[(q0-2)*4 .. (q0+6)*4), i.e. out range +/- 8
    float xs[NLOAD * 4];
#pragma unroll
    for (int t = 0; t < NLOAD; ++t) {
        int q = q0 - 2 + t;
        float4 v;
        if (q >= 0 && q < n4) {
            v = x4[q];
        } else {
            v = make_float4(NEG, NEG, NEG, NEG);
        }
        xs[4 * t + 0] = v.x;
        xs[4 * t + 1] = v.y;
        xs[4 * t + 2] = v.z;
        xs[4 * t + 3] = v.w;
    }
    // xs[8 + i]  <=>  x[q0*4 + i]

#pragma unroll
    for (int t = 0; t < VEC / 4; ++t) {
        if (q0 + t >= n4) break;
        float4 o;
        float* op = &o.x;
#pragma unroll
        for (int i = 0; i < 4; ++i) {
            int c = 8 + 4 * t + i;   // center of window in xs
            float m = xs[c - HALF] + h[0];
#pragma unroll
            for (int j = 1; j < KSZ; ++j) {
                m = fmaxf(m, xs[c - HALF + j] + h[j]);
            }
            op[i] = m;
        }
        out4[q0 + t] = o;
    }
}

extern "C" void kernel_launch(void* const* d_in, const int* in_sizes, int n_in,
                              void* d_out, int out_size, void* d_ws, size_t ws_size,
                              hipStream_t stream) {
    const float* x       = (const float*)d_in[0];
    const float* scale_p = (const float*)d_in[1];
    float*       out     = (float*)d_out;

    int n  = in_sizes[0];
    int n4 = n / 4;                      // n = 2^25, divisible by 4

    int threads_needed = (n4 + (VEC / 4) - 1) / (VEC / 4);
    int block = 256;
    int grid  = (threads_needed + block - 1) / block;

    dilate1d_kernel<<<grid, block, 0, stream>>>(
        (const float4*)x, scale_p, (float4*)out, n4);
}

// Round 2
// 231.059 us; speedup vs baseline: 1.0543x; 1.0543x over previous
//
#include <hip/hip_runtime.h>
#include <math.h>

// 1D grayscale dilation (max-plus conv), K=11, halo=5, fp32.
// out[i] = max_j ( x[i-5+j] + h[j] ),  h[j] = -(j-5)^2 / (4*scale)
//
// Round 1 lesson: thread-contiguous coarsening (16 floats/thread) gives a
// 64 B lane stride -> every VMEM instruction generates ~4x transactions and
// the kernel goes issue-bound at 2.2 TB/s. Fix: one float4 per thread per
// iteration (lane-contiguous, perfectly coalesced), grid-stride loop for
// coarsening. Halo = 5 overlapping float4 loads (offsets -32..+32 B), 4 of
// which hit L1.

#define KSZ  11
#define HALF 5
#define ITER 4   // grid sized so each thread runs exactly ITER iterations

__global__ __launch_bounds__(256) void dilate1d_kernel(
    const float4* __restrict__ x4,
    const float*  __restrict__ scale_p,
    float4*       __restrict__ out4,
    int n4)   // number of float4 elements in x / out
{
    const float s = scale_p[0];
    float h[KSZ];
#pragma unroll
    for (int j = 0; j < KSZ; ++j) {
        float z = (float)(j - HALF);
        h[j] = -(z * z) / (4.0f * s);
    }

    const float NEG = -INFINITY;
    const int stride = gridDim.x * blockDim.x;

    for (int q = blockIdx.x * blockDim.x + threadIdx.x; q < n4; q += stride) {
        // Stage 20 floats covering x[(q-2)*4 .. (q+3)*4) = out range +/- 8
        float xs[20];

        if (q >= 2 && q + 2 < n4) {
            // fast path (wave-uniform except 2 edge waves): 5 coalesced loads
#pragma unroll
            for (int t = 0; t < 5; ++t) {
                float4 v = x4[q - 2 + t];
                xs[4 * t + 0] = v.x;
                xs[4 * t + 1] = v.y;
                xs[4 * t + 2] = v.z;
                xs[4 * t + 3] = v.w;
            }
        } else {
#pragma unroll
            for (int t = 0; t < 5; ++t) {
                int qq = q - 2 + t;
                float4 v;
                if (qq >= 0 && qq < n4) v = x4[qq];
                else                    v = make_float4(NEG, NEG, NEG, NEG);
                xs[4 * t + 0] = v.x;
                xs[4 * t + 1] = v.y;
                xs[4 * t + 2] = v.z;
                xs[4 * t + 3] = v.w;
            }
        }
        // xs[8 + i] <=> x[q*4 + i]

        float4 o;
        float* op = &o.x;
#pragma unroll
        for (int i = 0; i < 4; ++i) {
            int c = 8 + i;  // center of window in xs
            float m = xs[c - HALF] + h[0];
#pragma unroll
            for (int j = 1; j < KSZ; ++j) {
                m = fmaxf(m, xs[c - HALF + j] + h[j]);
            }
            op[i] = m;
        }
        out4[q] = o;
    }
}

extern "C" void kernel_launch(void* const* d_in, const int* in_sizes, int n_in,
                              void* d_out, int out_size, void* d_ws, size_t ws_size,
                              hipStream_t stream) {
    const float* x       = (const float*)d_in[0];
    const float* scale_p = (const float*)d_in[1];
    float*       out     = (float*)d_out;

    int n  = in_sizes[0];
    int n4 = n / 4;                      // n = 2^25 -> n4 = 2^23

    int block = 256;
    // Size grid so each thread iterates ITER times (exact for n = 2^25).
    long long threads_wanted = (long long)(n4 + ITER - 1) / ITER;
    int grid = (int)((threads_wanted + block - 1) / block);

    dilate1d_kernel<<<grid, block, 0, stream>>>(
        (const float4*)x, scale_p, (float4*)out, n4);
}